// Round 7
// baseline (471.509 us; speedup 1.0000x reference)
//
#include <hip/hip_runtime.h>

#define N 100000
#define E 1000000
#define ETOT 1100000   // E + N self-loops
#define NB1 391        // ceil(N/256)

typedef __attribute__((ext_vector_type(8))) short bf16x8;
typedef __attribute__((ext_vector_type(4))) float f32x4;

__device__ __forceinline__ float lrelu(float x) { return x > 0.f ? x : 0.2f * x; }
// f32 -> bf16 bits, round-to-nearest-even
__device__ __forceinline__ unsigned short f2b(float x) {
    unsigned u = __float_as_uint(x);
    return (unsigned short)((u + 0x7FFFu + ((u >> 16) & 1u)) >> 16);
}
__device__ __forceinline__ float b2f(unsigned short v) {
    return __uint_as_float(((unsigned)v) << 16);
}

// ---------------- CSR build ----------------
__global__ __launch_bounds__(256) void hist_kernel(const int* __restrict__ ei,
                                                   int* __restrict__ hist) {
    const int e = blockIdx.x * 256 + threadIdx.x;
    if (e >= ETOT) return;
    int d = (e < E) ? ei[E + e] : (e - E);
    atomicAdd(&hist[d], 1);
}

__global__ __launch_bounds__(256) void scan1_kernel(const int* __restrict__ hist,
                                                    int* __restrict__ rofs,
                                                    int* __restrict__ bsum) {
    __shared__ int sm[256];
    const int t = threadIdx.x;
    const int i = blockIdx.x * 256 + t;
    int v = (i < N) ? hist[i] : 0;
    sm[t] = v;
    __syncthreads();
#pragma unroll
    for (int off = 1; off < 256; off <<= 1) {
        int x = (t >= off) ? sm[t - off] : 0;
        __syncthreads();
        sm[t] += x;
        __syncthreads();
    }
    if (i < N) rofs[i] = sm[t] - v;
    if (t == 255) bsum[blockIdx.x] = sm[255];
}

__global__ __launch_bounds__(512) void scan2_kernel(int* __restrict__ bsum) {
    __shared__ int sm[512];
    const int t = threadIdx.x;
    int v = (t < NB1) ? bsum[t] : 0;
    sm[t] = v;
    __syncthreads();
#pragma unroll
    for (int off = 1; off < 512; off <<= 1) {
        int x = (t >= off) ? sm[t - off] : 0;
        __syncthreads();
        sm[t] += x;
        __syncthreads();
    }
    if (t < NB1) bsum[t] = sm[t] - v;
}

__global__ __launch_bounds__(256) void scan3_kernel(int* __restrict__ rofs,
                                                    const int* __restrict__ bsum,
                                                    int* __restrict__ cursor) {
    const int i = blockIdx.x * 256 + threadIdx.x;
    if (i < N) {
        int r = rofs[i] + bsum[blockIdx.x];
        rofs[i] = r;
        cursor[i] = r;
    }
    if (i == 0) rofs[N] = ETOT;
}

__global__ __launch_bounds__(256) void scatter_kernel(const int* __restrict__ ei,
                                                      int* __restrict__ cursor,
                                                      int* __restrict__ esrc) {
    const int e = blockIdx.x * 256 + threadIdx.x;
    if (e >= ETOT) return;
    int s, d;
    if (e < E) { s = ei[e]; d = ei[E + e]; } else { s = d = e - E; }
    int pos = atomicAdd(&cursor[d], 1);
    esrc[pos] = s;
}

// ---------------- weight prep (bf16): W1T rows 0..255, logit-fold rows 256..271, W2T ----------------
__global__ __launch_bounds__(256) void wt_kernel(const float* __restrict__ W1,
                                                 const float* __restrict__ W2,
                                                 const float* __restrict__ att_src1,
                                                 const float* __restrict__ att_dst1,
                                                 unsigned short* __restrict__ W1T,
                                                 unsigned short* __restrict__ W2T) {
    const int b = blockIdx.x;
    const int t = threadIdx.x;
    if (b < 128) {
        W1T[(size_t)t * 128 + b] = f2b(W1[(size_t)b * 256 + t]);
    } else if (b < 160) {
        int n = b - 128;
        W2T[(size_t)n * 256 + t] = f2b(W2[(size_t)t * 32 + n]);
    } else {
        int idx = (b - 160) * 256 + t;          // 0..2047
        int col = idx >> 7;                     // 0..15
        int k = idx & 127;
        int h = col & 7;
        const float* att = (col < 8) ? att_src1 : att_dst1;
        float acc = 0.f;
#pragma unroll 8
        for (int j = 0; j < 32; j++) acc += W1[(size_t)k * 256 + h * 32 + j] * att[h * 32 + j];
        W1T[(size_t)(256 + col) * 128 + k] = f2b(acc);
    }
}

// ---------------- layer 1 GEMM via MFMA bf16: h1 = x0 @ W1 (+ fused logits) ----------------
__global__ __launch_bounds__(256) void gemm1_kernel(const float* __restrict__ x0,
                                                    const unsigned short* __restrict__ W1T,
                                                    unsigned short* __restrict__ h1,
                                                    float* __restrict__ a_src,
                                                    float* __restrict__ a_dst) {
    const int wv = threadIdx.x >> 6;
    const int lane = threadIdx.x & 63;
    const int quad = lane >> 4, c = lane & 15;
    const int base_m = blockIdx.x * 128 + wv * 32;
    bf16x8 af[2][4];
#pragma unroll
    for (int mt = 0; mt < 2; mt++) {
        int row = base_m + mt * 16 + c;
        int rowc = row < N ? row : N - 1;
        const float* ap = x0 + (size_t)rowc * 128 + quad * 8;
#pragma unroll
        for (int ks = 0; ks < 4; ks++) {
            float4 lo = *(const float4*)(ap + ks * 32);
            float4 hi = *(const float4*)(ap + ks * 32 + 4);
            bf16x8 f;
            f[0] = (short)f2b(lo.x); f[1] = (short)f2b(lo.y);
            f[2] = (short)f2b(lo.z); f[3] = (short)f2b(lo.w);
            f[4] = (short)f2b(hi.x); f[5] = (short)f2b(hi.y);
            f[6] = (short)f2b(hi.z); f[7] = (short)f2b(hi.w);
            af[mt][ks] = f;
        }
    }
    for (int nt = 0; nt < 17; nt++) {
        f32x4 acc0 = {0.f, 0.f, 0.f, 0.f};
        f32x4 acc1 = {0.f, 0.f, 0.f, 0.f};
#pragma unroll
        for (int ks = 0; ks < 4; ks++) {
            bf16x8 bf = *(const bf16x8*)(W1T + (size_t)(nt * 16 + c) * 128 + ks * 32 + quad * 8);
            acc0 = __builtin_amdgcn_mfma_f32_16x16x32_bf16(af[0][ks], bf, acc0, 0, 0, 0);
            acc1 = __builtin_amdgcn_mfma_f32_16x16x32_bf16(af[1][ks], bf, acc1, 0, 0, 0);
        }
        if (nt < 16) {
            const int col = nt * 16 + c;
#pragma unroll
            for (int r = 0; r < 4; r++) {
                int row0 = base_m + quad * 4 + r;
                if (row0 < N) h1[(size_t)row0 * 256 + col] = f2b(acc0[r]);
                int row1 = base_m + 16 + quad * 4 + r;
                if (row1 < N) h1[(size_t)row1 * 256 + col] = f2b(acc1[r]);
            }
        } else {
            float* dst = (c < 8) ? a_src : a_dst;
            int hh = c & 7;
#pragma unroll
            for (int r = 0; r < 4; r++) {
                int row0 = base_m + quad * 4 + r;
                if (row0 < N) dst[(size_t)row0 * 8 + hh] = acc0[r];
                int row1 = base_m + 16 + quad * 4 + r;
                if (row1 < N) dst[(size_t)row1 * 8 + hh] = acc1[r];
            }
        }
    }
}

// ---------------- layer 1 aggregate: wave/node, 8 masked chains (max MLP) ----------------
__global__ __launch_bounds__(256) void seg1_kernel(const int* __restrict__ esrc,
                                                   const int* __restrict__ rofs,
                                                   const float* __restrict__ a_src,
                                                   const float* __restrict__ a_dst,
                                                   const unsigned short* __restrict__ h1,
                                                   const float* __restrict__ b1,
                                                   unsigned short* __restrict__ x2) {
    const int n = (blockIdx.x * 256 + threadIdx.x) >> 6;
    const int lane = threadIdx.x & 63;
    const int h = lane >> 3;
    if (n >= N) return;
    const int rs = rofs[n], re = rofs[n + 1];
    const float ad = a_dst[(size_t)n * 8 + h];
    float d[8] = {0, 0, 0, 0, 0, 0, 0, 0};
    float4 A[8] = {{0,0,0,0},{0,0,0,0},{0,0,0,0},{0,0,0,0},{0,0,0,0},{0,0,0,0},{0,0,0,0},{0,0,0,0}};
    for (int j0 = rs; j0 < re; j0 += 8) {
        int sidx[8];
#pragma unroll
        for (int k = 0; k < 8; k++) {
            int j = j0 + k;
            sidx[k] = esrc[j < re ? j : re - 1];
        }
        ushort4 hb[8];
        float as[8];
#pragma unroll
        for (int k = 0; k < 8; k++) {
            hb[k] = ((const ushort4*)(h1 + (size_t)sidx[k] * 256))[lane];
            as[k] = a_src[(size_t)sidx[k] * 8 + h];
        }
#pragma unroll
        for (int k = 0; k < 8; k++) {
            float w = (j0 + k < re) ? __expf(lrelu(as[k] + ad)) : 0.f;
            d[k] += w;
            A[k].x += w * b2f(hb[k].x);
            A[k].y += w * b2f(hb[k].y);
            A[k].z += w * b2f(hb[k].z);
            A[k].w += w * b2f(hb[k].w);
        }
    }
    float den = ((d[0] + d[1]) + (d[2] + d[3])) + ((d[4] + d[5]) + (d[6] + d[7]));
    float4 acc;
    acc.x = ((A[0].x + A[1].x) + (A[2].x + A[3].x)) + ((A[4].x + A[5].x) + (A[6].x + A[7].x));
    acc.y = ((A[0].y + A[1].y) + (A[2].y + A[3].y)) + ((A[4].y + A[5].y) + (A[6].y + A[7].y));
    acc.z = ((A[0].z + A[1].z) + (A[2].z + A[3].z)) + ((A[4].z + A[5].z) + (A[6].z + A[7].z));
    acc.w = ((A[0].w + A[1].w) + (A[2].w + A[3].w)) + ((A[4].w + A[5].w) + (A[6].w + A[7].w));
    const float inv = 1.0f / den;
    float4 bb = ((const float4*)b1)[lane];
    float vx = acc.x * inv + bb.x, vy = acc.y * inv + bb.y;
    float vz = acc.z * inv + bb.z, vw = acc.w * inv + bb.w;
    vx = vx > 0.f ? vx : 0.f; vy = vy > 0.f ? vy : 0.f;
    vz = vz > 0.f ? vz : 0.f; vw = vw > 0.f ? vw : 0.f;
    ushort4 o = {f2b(vx), f2b(vy), f2b(vz), f2b(vw)};
    ((ushort4*)(x2 + (size_t)n * 256))[lane] = o;
}

// ---------------- layer 2 GEMM via MFMA: h2 = x2 @ W2 (256->32), fused logits ----------------
__global__ __launch_bounds__(256) void gemm2_kernel(const unsigned short* __restrict__ x2,
                                                    const unsigned short* __restrict__ W2T,
                                                    const float* __restrict__ att_src2,
                                                    const float* __restrict__ att_dst2,
                                                    unsigned short* __restrict__ h2,
                                                    float* __restrict__ a_src2,
                                                    float* __restrict__ a_dst2) {
    const int wv = threadIdx.x >> 6;
    const int lane = threadIdx.x & 63;
    const int quad = lane >> 4, c = lane & 15;
    const int base_m = blockIdx.x * 128 + wv * 32;
    f32x4 acc[2][2] = {{{0, 0, 0, 0}, {0, 0, 0, 0}}, {{0, 0, 0, 0}, {0, 0, 0, 0}}};
#pragma unroll
    for (int ks = 0; ks < 8; ks++) {
        bf16x8 b0 = *(const bf16x8*)(W2T + (size_t)c * 256 + ks * 32 + quad * 8);
        bf16x8 b1 = *(const bf16x8*)(W2T + (size_t)(16 + c) * 256 + ks * 32 + quad * 8);
#pragma unroll
        for (int mt = 0; mt < 2; mt++) {
            int row = base_m + mt * 16 + c;
            int rowc = row < N ? row : N - 1;
            bf16x8 a = *(const bf16x8*)(x2 + (size_t)rowc * 256 + ks * 32 + quad * 8);
            acc[mt][0] = __builtin_amdgcn_mfma_f32_16x16x32_bf16(a, b0, acc[mt][0], 0, 0, 0);
            acc[mt][1] = __builtin_amdgcn_mfma_f32_16x16x32_bf16(a, b1, acc[mt][1], 0, 0, 0);
        }
    }
    float as0 = att_src2[c], as1 = att_src2[16 + c];
    float ad0 = att_dst2[c], ad1 = att_dst2[16 + c];
#pragma unroll
    for (int mt = 0; mt < 2; mt++) {
#pragma unroll
        for (int r = 0; r < 4; r++) {
            int row = base_m + mt * 16 + quad * 4 + r;
            float v0 = acc[mt][0][r], v1 = acc[mt][1][r];
            float ps = v0 * as0 + v1 * as1;
            float pd = v0 * ad0 + v1 * ad1;
#pragma unroll
            for (int off = 1; off < 16; off <<= 1) {
                ps += __shfl_xor(ps, off, 64);
                pd += __shfl_xor(pd, off, 64);
            }
            if (row < N) {
                h2[(size_t)row * 32 + c] = f2b(v0);
                h2[(size_t)row * 32 + 16 + c] = f2b(v1);
                if (c == 0) { a_src2[row] = ps; a_dst2[row] = pd; }
            }
        }
    }
}

// ---------------- layer 2 aggregate + final linear fused: half-wave/node, 8 chains ----------------
__global__ __launch_bounds__(256) void seg2_kernel(const int* __restrict__ esrc,
                                                   const int* __restrict__ rofs,
                                                   const float* __restrict__ a_src2,
                                                   const float* __restrict__ a_dst2,
                                                   const unsigned short* __restrict__ h2,
                                                   const float* __restrict__ b2,
                                                   const float* __restrict__ linW,
                                                   const float* __restrict__ linb,
                                                   float* __restrict__ out) {
    __shared__ float lws[32 * 40];
    __shared__ float vbuf[8][32];
    const int t = threadIdx.x;
    for (int i = t; i < 1280; i += 256) lws[i] = linW[i];
    const int n8 = t >> 5;
    const int c = t & 31;
    const int n = blockIdx.x * 8 + n8;      // N % 8 == 0, grid = N/8 -> always valid
    const int rs = rofs[n], re = rofs[n + 1];
    const float ad = a_dst2[n];
    float d[8] = {0, 0, 0, 0, 0, 0, 0, 0};
    float A[8] = {0, 0, 0, 0, 0, 0, 0, 0};
    for (int j0 = rs; j0 < re; j0 += 8) {
        int sidx[8];
#pragma unroll
        for (int k = 0; k < 8; k++) {
            int j = j0 + k;
            sidx[k] = esrc[j < re ? j : re - 1];
        }
        unsigned short hb[8];
        float as[8];
#pragma unroll
        for (int k = 0; k < 8; k++) {
            hb[k] = h2[(size_t)sidx[k] * 32 + c];
            as[k] = a_src2[sidx[k]];
        }
#pragma unroll
        for (int k = 0; k < 8; k++) {
            float w = (j0 + k < re) ? __expf(lrelu(as[k] + ad)) : 0.f;
            d[k] += w;
            A[k] += w * b2f(hb[k]);
        }
    }
    float den = ((d[0] + d[1]) + (d[2] + d[3])) + ((d[4] + d[5]) + (d[6] + d[7]));
    float acc = ((A[0] + A[1]) + (A[2] + A[3])) + ((A[4] + A[5]) + (A[6] + A[7]));
    vbuf[n8][c] = acc / den + b2[c];
    __syncthreads();
    // 8 nodes x 40 outputs = 320 values, coalesced
    for (int idx = t; idx < 320; idx += 256) {
        int nn = idx / 40, o = idx - nn * 40;
        float s = linb[o];
#pragma unroll
        for (int ci = 0; ci < 32; ci++) s += vbuf[nn][ci] * lws[ci * 40 + o];
        out[(size_t)blockIdx.x * 320 + idx] = s;
    }
}

extern "C" void kernel_launch(void* const* d_in, const int* in_sizes, int n_in,
                              void* d_out, int out_size, void* d_ws, size_t ws_size,
                              hipStream_t stream) {
    const float* x0       = (const float*)d_in[0];
    const float* W1       = (const float*)d_in[1];
    const float* att_src1 = (const float*)d_in[2];
    const float* att_dst1 = (const float*)d_in[3];
    const float* b1       = (const float*)d_in[4];
    const float* W2       = (const float*)d_in[5];
    const float* att_src2 = (const float*)d_in[6];
    const float* att_dst2 = (const float*)d_in[7];
    const float* b2       = (const float*)d_in[8];
    const float* linW     = (const float*)d_in[9];
    const float* linb     = (const float*)d_in[10];
    const int*   ei       = (const int*)d_in[11];
    float* out = (float*)d_out;
    float* ws  = (float*)d_ws;

    unsigned short* h1  = (unsigned short*)ws;                  // 25.6M bf16
    unsigned short* x2  = (unsigned short*)(ws + 12800000);     // 25.6M bf16
    float* a_src1       = ws + 25600000;                        // 0.8M
    float* a_dst1       = ws + 26400000;                        // 0.8M
    unsigned short* h2  = (unsigned short*)(ws + 27200000);     // 3.2M bf16
    float* a_src2       = ws + 28800000;                        // 0.1M
    float* a_dst2       = ws + 28900000;                        // 0.1M
    unsigned short* W1T = (unsigned short*)(ws + 29000000);     // 272*128 bf16
    unsigned short* W2T = (unsigned short*)(ws + 29020000);     // 8192 bf16
    int*   hist         = (int*)(ws + 29030000);                // 0.1M
    int*   rofs         = (int*)(ws + 29130000);                // N+1
    int*   cursor       = (int*)(ws + 29240000);                // 0.1M
    int*   bsum         = (int*)(ws + 29340000);                // 512
    int*   esrc         = (int*)(ws + 29341000);                // 1.1M

    hipMemsetAsync(hist, 0, (size_t)N * 4, stream);

    hist_kernel<<<(ETOT + 255) / 256, 256, 0, stream>>>(ei, hist);
    scan1_kernel<<<NB1, 256, 0, stream>>>(hist, rofs, bsum);
    scan2_kernel<<<1, 512, 0, stream>>>(bsum);
    scan3_kernel<<<NB1, 256, 0, stream>>>(rofs, bsum, cursor);
    scatter_kernel<<<(ETOT + 255) / 256, 256, 0, stream>>>(ei, cursor, esrc);

    wt_kernel<<<168, 256, 0, stream>>>(W1, W2, att_src1, att_dst1, W1T, W2T);
    gemm1_kernel<<<(N + 127) / 128, 256, 0, stream>>>(x0, W1T, h1, a_src1, a_dst1);
    seg1_kernel<<<N / 4, 256, 0, stream>>>(esrc, rofs, a_src1, a_dst1, h1, b1, x2);
    gemm2_kernel<<<(N + 127) / 128, 256, 0, stream>>>(x2, W2T, att_src2, att_dst2, h2, a_src2, a_dst2);
    seg2_kernel<<<N / 8, 256, 0, stream>>>(esrc, rofs, a_src2, a_dst2, h2, b2, linW, linb, out);
}